// Round 14
// baseline (283.949 us; speedup 1.0000x reference)
//
#include <hip/hip_runtime.h>
#include <cstdint>

// ---------------------------------------------------------------------------
// TinyViT block on gfx950. Round 14:
//  - X1 (proj output / conv input) stored bf16: proj WRITE halves, conv
//    FETCH halves. (MODE 5 epilogue: bf16 out = acc + bias + f32 res.)
//  - qkv moved to the BK=64/TN=64 dual-buffer GEMM (half the barriers),
//    matching the fc1/fc2/proj configuration.
//  - everything else frozen from round 13 (swizzled LDS, bf16 X2, token-
//    compact pipeline, fused prep, token-gather MFMA attention).
// ---------------------------------------------------------------------------

typedef __bf16 bf16x8 __attribute__((ext_vector_type(8)));
typedef __bf16 bf16x4 __attribute__((ext_vector_type(4)));
typedef float  f32x4  __attribute__((ext_vector_type(4)));

#define DIM_    384
#define QKVD    1152
#define HIDD    1536
#define NTOK    49
#define NWIN    400
#define TOKENS  16384     /* 4*4096 real tokens */
#define PADROW  16384     /* shared pad-token row index */
#define MQKV    16512     /* 129*128 */
#define SCALE_  0.17677669529663689f
#define EPS_    1e-5f

// prep job block ranges (256 threads each)
#define B_LN1   8192      /* 16384 tokens, 2 per block */
#define B_PADR  1
#define B_TQKV  108       /* 64x64 tiles: 6 x 18 */
#define B_TPROJ 36        /* 6 x 6   */
#define B_TFC1  144       /* 6 x 24  */
#define B_TFC2  144       /* 24 x 6  */
#define B_CONV  14
#define B_BIAS  192
#define B_TOTAL (B_LN1 + B_PADR + B_TQKV + B_TPROJ + B_TFC1 + B_TFC2 + B_CONV + B_BIAS)

__device__ __forceinline__ void gload_lds16(const void* g, void* l) {
  __builtin_amdgcn_global_load_lds(
      (__attribute__((address_space(1))) void*)g,
      (__attribute__((address_space(3))) void*)l, 16, 0, 0);
}

// tanh-form GELU via sigmoid + fast rcp
__device__ __forceinline__ float gelu_fast(float v) {
  float t2 = v * (1.5957691216057308f + 0.07135481627f * v * v);
  return v * __builtin_amdgcn_rcpf(1.f + __expf(-t2));
}

// 64x64 tile transpose: src (KxN fp32) -> dst (NxK bf16), coalesced both sides.
__device__ __forceinline__ void tile_transpose(
    const float* __restrict__ src, __bf16* __restrict__ dst,
    int K, int N, int tile, int tilesN, __bf16 (*ld)[65]) {
  int kt = tile / tilesN, nt = tile % tilesN;
  int k0 = kt * 64, n0 = nt * 64;
  int tid = threadIdx.x;
  int a = tid & 63, b4 = tid >> 6;
  #pragma unroll
  for (int i = 0; i < 16; i++) {
    int kl = b4 + i * 4;
    ld[kl][a] = (__bf16)src[(long)(k0 + kl) * N + n0 + a];   // coalesced read
  }
  __syncthreads();
  #pragma unroll
  for (int i = 0; i < 16; i++) {
    int nl = b4 + i * 4;
    dst[(long)(n0 + nl) * K + k0 + a] = ld[a][nl];           // coalesced write
  }
}

// ---------------------------------------------------------------------------
// Fused prep: LN1, shared pad row, tiled weight transposes, conv-w, bias.
// ---------------------------------------------------------------------------
__global__ __launch_bounds__(256) void prep_all(
    const float* __restrict__ x, const float* __restrict__ ln1_g,
    const float* __restrict__ ln1_b, __bf16* __restrict__ xn,
    const float* __restrict__ qkv_w,  __bf16* __restrict__ wqkv,
    const float* __restrict__ proj_w, __bf16* __restrict__ wproj,
    const float* __restrict__ fc1_w,  __bf16* __restrict__ wfc1,
    const float* __restrict__ fc2_w,  __bf16* __restrict__ wfc2,
    const float* __restrict__ conv_w, float* __restrict__ wconv,
    const float* __restrict__ attn_b, float* __restrict__ bm) {
  __shared__ __bf16 tlds[64][65];
  __shared__ float red[2][4];
  int b = blockIdx.x;
  int tid = threadIdx.x;

  if (b < B_LN1) {
    int sub = tid >> 7, tl = tid & 127;
    long t = (long)b * 2 + sub;                // 0..16383
    const float* xr = x + t * DIM_;
    float v0 = xr[tl], v1 = xr[tl + 128], v2 = xr[tl + 256];
    float s = v0 + v1 + v2, s2 = v0 * v0 + v1 * v1 + v2 * v2;
    for (int off = 32; off; off >>= 1) { s += __shfl_down(s, off); s2 += __shfl_down(s2, off); }
    if ((tl & 63) == 0) { red[sub][tl >> 6] = s; red[sub][2 + (tl >> 6)] = s2; }
    __syncthreads();
    float S = red[sub][0] + red[sub][1], S2 = red[sub][2] + red[sub][3];
    float m  = S * (1.f / DIM_);
    float rs = rsqrtf(S2 * (1.f / DIM_) - m * m + EPS_);
    __bf16* orow = xn + t * DIM_;
    orow[tl]       = (__bf16)((v0 - m) * rs * ln1_g[tl]       + ln1_b[tl]);
    orow[tl + 128] = (__bf16)((v1 - m) * rs * ln1_g[tl + 128] + ln1_b[tl + 128]);
    orow[tl + 256] = (__bf16)((v2 - m) * rs * ln1_g[tl + 256] + ln1_b[tl + 256]);
    return;
  }
  b -= B_LN1;
  if (b < B_PADR) {              // shared pad-token row: LN(0-pad) = ln1_b
    for (int i = tid; i < DIM_; i += 256)
      xn[(long)PADROW * DIM_ + i] = (__bf16)ln1_b[i];
    return;
  }
  b -= B_PADR;
  if (b < B_TQKV)  { tile_transpose(qkv_w,  wqkv,  DIM_, QKVD, b, 18, tlds); return; }
  b -= B_TQKV;
  if (b < B_TPROJ) { tile_transpose(proj_w, wproj, DIM_, DIM_, b, 6,  tlds); return; }
  b -= B_TPROJ;
  if (b < B_TFC1)  { tile_transpose(fc1_w,  wfc1,  DIM_, HIDD, b, 24, tlds); return; }
  b -= B_TFC1;
  if (b < B_TFC2)  { tile_transpose(fc2_w,  wfc2,  HIDD, DIM_, b, 6,  tlds); return; }
  b -= B_TFC2;
  if (b < B_CONV) {              // conv_w [384][9] -> wconv [9][384]
    int id = b * 256 + tid;
    if (id < 3456) {
      int ch = id / 9, k = id % 9;
      wconv[k * DIM_ + ch] = conv_w[id];
    }
    return;
  }
  b -= B_CONV;
  {                              // bias table bm[12][64][64], mask kk>=49
    int id = b * 256 + tid;
    int h = id >> 12, q = (id >> 6) & 63, kk = id & 63;
    float v;
    if (kk >= NTOK)      v = -1e30f;
    else if (q >= NTOK)  v = 0.f;
    else {
      int idx = abs(q / 7 - kk / 7) * 7 + abs(q % 7 - kk % 7);
      v = attn_b[h * NTOK + idx];
    }
    bm[id] = v;
  }
}

// ---------------------------------------------------------------------------
// Fused depthwise 3x3 conv + BN + LN2. Block = 4 pixels x 96 lanes (384 thr).
// X1 input now bf16; X2 (fc2 residual) and XLN2 written bf16.
// ---------------------------------------------------------------------------
__global__ __launch_bounds__(384) void conv_bn_ln2(
    const __bf16* __restrict__ x1, const float* __restrict__ wT,
    const float* __restrict__ bng, const float* __restrict__ bnb,
    const float* __restrict__ mean, const float* __restrict__ var,
    const float* __restrict__ g2, const float* __restrict__ b2,
    __bf16* __restrict__ x2, __bf16* __restrict__ xln2) {
  int tid = threadIdx.x;
  int p = tid / 96, g = tid % 96;
  int pix = blockIdx.x * 4 + p;            // 0..16383
  int bb = pix >> 12, rc = pix & 4095;
  int r = rc >> 6, c = rc & 63;
  int ch = g << 2;

  f32x4 acc = (f32x4){0.f, 0.f, 0.f, 0.f};
  #pragma unroll
  for (int dr = -1; dr <= 1; dr++) {
    int rr = r + dr;
    if (rr < 0 || rr >= 64) continue;
    #pragma unroll
    for (int dc = -1; dc <= 1; dc++) {
      int cc = c + dc;
      if (cc < 0 || cc >= 64) continue;
      bf16x4 xb = *(const bf16x4*)(x1 + ((long)bb * 4096 + rr * 64 + cc) * DIM_ + ch);
      f32x4 wv = *(const f32x4*)(wT + ((dr + 1) * 3 + (dc + 1)) * DIM_ + ch);
      #pragma unroll
      for (int j = 0; j < 4; j++) acc[j] += (float)xb[j] * wv[j];
    }
  }

  f32x4 gv = *(const f32x4*)(bng + ch);
  f32x4 vv = *(const f32x4*)(var + ch);
  f32x4 mv = *(const f32x4*)(mean + ch);
  f32x4 bv = *(const f32x4*)(bnb + ch);
  f32x4 y;
  #pragma unroll
  for (int j = 0; j < 4; j++) {
    float sc = gv[j] * rsqrtf(vv[j] + EPS_);
    y[j] = acc[j] * sc + (bv[j] - mv[j] * sc);
  }
  {
    bf16x4 xv2;
    #pragma unroll
    for (int j = 0; j < 4; j++) xv2[j] = (__bf16)y[j];
    *(bf16x4*)(x2 + (long)pix * DIM_ + ch) = xv2;
  }

  __shared__ float pS[4][96], pS2[4][96], mS[4], rS[4];
  pS[p][g]  = y[0] + y[1] + y[2] + y[3];
  pS2[p][g] = y[0] * y[0] + y[1] * y[1] + y[2] * y[2] + y[3] * y[3];
  __syncthreads();
  if (g < 32) {
    float a  = pS[p][g]  + pS[p][g + 32]  + pS[p][g + 64];
    float a2 = pS2[p][g] + pS2[p][g + 32] + pS2[p][g + 64];
    #pragma unroll
    for (int off = 1; off < 32; off <<= 1) {
      a  += __shfl_xor(a, off);
      a2 += __shfl_xor(a2, off);
    }
    if (g == 0) {
      float m = a * (1.f / DIM_);
      mS[p] = m;
      rS[p] = rsqrtf(a2 * (1.f / DIM_) - m * m + EPS_);
    }
  }
  __syncthreads();
  float m = mS[p], rs = rS[p];
  f32x4 gg = *(const f32x4*)(g2 + ch);
  f32x4 b2v = *(const f32x4*)(b2 + ch);
  bf16x4 ov;
  #pragma unroll
  for (int j = 0; j < 4; j++) ov[j] = (__bf16)((y[j] - m) * rs * gg[j] + b2v[j]);
  *(bf16x4*)(xln2 + (long)pix * DIM_ + ch) = ov;
}

// ---------------------------------------------------------------------------
// MFMA attention, token-gather version (round-9, verified).
// ---------------------------------------------------------------------------
__global__ __launch_bounds__(64) void attn_mfma(const __bf16* __restrict__ qkv,
                                                const float* __restrict__ bm,
                                                __bf16* __restrict__ o) {
  int blk = blockIdx.x;
  int win = blk / 12, h = blk % 12;
  int bb = win / 100, rem = win % 100;
  int wy = rem / 10, wx = rem % 10;
  int lane = threadIdx.x;
  int quad = lane >> 4, l16 = lane & 15;

  __shared__ __align__(16) __bf16 Vt[32][72];   // Vt[d][kk]
  __shared__ __align__(16) __bf16 P[64][72];    // P[q][kk]

  const __bf16* base = qkv + h * 96;

  bf16x8 qf[4], kf[4];
  #pragma unroll
  for (int mt = 0; mt < 4; mt++) {
    int t = mt * 16 + l16;
    int ty = t / 7, tx = t % 7;
    int r = wy * 7 + ty, c = wx * 7 + tx;
    int row = (t < NTOK && r < 64 && c < 64) ? (bb * 4096 + r * 64 + c) : PADROW;
    const __bf16* rp = base + (long)row * QKVD + quad * 8;
    qf[mt] = *(const bf16x8*)(rp);
    kf[mt] = *(const bf16x8*)(rp + 32);
  }
  {
    int t = lane;
    int ty = t / 7, tx = t % 7;
    int r = wy * 7 + ty, c = wx * 7 + tx;
    int row = (t < NTOK && r < 64 && c < 64) ? (bb * 4096 + r * 64 + c) : PADROW;
    const __bf16* vp = base + (long)row * QKVD + 64;
    bf16x8 vv[4];
    #pragma unroll
    for (int i = 0; i < 4; i++) vv[i] = *(const bf16x8*)(vp + i * 8);
    #pragma unroll
    for (int i = 0; i < 4; i++)
      #pragma unroll
      for (int j = 0; j < 8; j++) Vt[i * 8 + j][lane] = vv[i][j];
  }

  f32x4 S[4][4];
  #pragma unroll
  for (int i = 0; i < 4; i++)
    #pragma unroll
    for (int j = 0; j < 4; j++) S[i][j] = (f32x4){0.f, 0.f, 0.f, 0.f};
  #pragma unroll
  for (int mt = 0; mt < 4; mt++)
    #pragma unroll
    for (int nt = 0; nt < 4; nt++)
      S[mt][nt] = __builtin_amdgcn_mfma_f32_16x16x32_bf16(qf[mt], kf[nt], S[mt][nt], 0, 0, 0);

  const float* bmh = bm + h * 4096;
  #pragma unroll
  for (int mt = 0; mt < 4; mt++)
    #pragma unroll
    for (int r = 0; r < 4; r++) {
      int q = mt * 16 + quad * 4 + r;
      #pragma unroll
      for (int nt = 0; nt < 4; nt++)
        S[mt][nt][r] = S[mt][nt][r] * SCALE_ + bmh[q * 64 + nt * 16 + l16];
    }

  #pragma unroll
  for (int mt = 0; mt < 4; mt++)
    #pragma unroll
    for (int r = 0; r < 4; r++) {
      float mx = fmaxf(fmaxf(S[mt][0][r], S[mt][1][r]), fmaxf(S[mt][2][r], S[mt][3][r]));
      #pragma unroll
      for (int off = 1; off < 16; off <<= 1) mx = fmaxf(mx, __shfl_xor(mx, off));
      float sum = 0.f;
      #pragma unroll
      for (int nt = 0; nt < 4; nt++) {
        float e = __expf(S[mt][nt][r] - mx);
        S[mt][nt][r] = e;
        sum += e;
      }
      #pragma unroll
      for (int off = 1; off < 16; off <<= 1) sum += __shfl_xor(sum, off);
      float inv = 1.f / sum;
      #pragma unroll
      for (int nt = 0; nt < 4; nt++) S[mt][nt][r] *= inv;
    }

  #pragma unroll
  for (int mt = 0; mt < 4; mt++)
    #pragma unroll
    for (int r = 0; r < 4; r++) {
      int q = mt * 16 + quad * 4 + r;
      #pragma unroll
      for (int nt = 0; nt < 4; nt++)
        P[q][nt * 16 + l16] = (__bf16)S[mt][nt][r];
    }
  __syncthreads();

  f32x4 O[4][2];
  #pragma unroll
  for (int i = 0; i < 4; i++)
    #pragma unroll
    for (int j = 0; j < 2; j++) O[i][j] = (f32x4){0.f, 0.f, 0.f, 0.f};
  #pragma unroll
  for (int kt = 0; kt < 2; kt++) {
    bf16x8 pf[4], vf[2];
    #pragma unroll
    for (int mt = 0; mt < 4; mt++)
      pf[mt] = *(const bf16x8*)(&P[mt * 16 + l16][kt * 32 + quad * 8]);
    #pragma unroll
    for (int nt = 0; nt < 2; nt++)
      vf[nt] = *(const bf16x8*)(&Vt[nt * 16 + l16][kt * 32 + quad * 8]);
    #pragma unroll
    for (int mt = 0; mt < 4; mt++)
      #pragma unroll
      for (int nt = 0; nt < 2; nt++)
        O[mt][nt] = __builtin_amdgcn_mfma_f32_16x16x32_bf16(pf[mt], vf[nt], O[mt][nt], 0, 0, 0);
  }

  #pragma unroll
  for (int mt = 0; mt < 4; mt++)
    #pragma unroll
    for (int r = 0; r < 4; r++) {
      int q = mt * 16 + quad * 4 + r;
      if (q < NTOK) {
        int ty = q / 7, tx = q % 7;
        int rr = wy * 7 + ty, cc = wx * 7 + tx;
        if (rr < 64 && cc < 64) {
          __bf16* ob = o + ((long)bb * 4096 + rr * 64 + cc) * DIM_ + h * 32;
          #pragma unroll
          for (int nt = 0; nt < 2; nt++)
            ob[nt * 16 + l16] = (__bf16)O[mt][nt][r];
        }
      }
    }
}

// ---------------------------------------------------------------------------
// BK=64 dual-buffer GEMM, TN=64 (24KB LDS), swizzled LDS layout.
// Used for ALL four GEMMs now.
// MODE 0: bf16 out = acc + bias                 (qkv)
// MODE 2: bf16 out = gelu_fast(acc + bias)      (fc1)
// MODE 4: f32  out = acc + bias + bf16 res      (fc2 -> OUT)
// MODE 5: bf16 out = acc + bias + f32 res       (proj -> X1)
// K must be a multiple of 64.
// ---------------------------------------------------------------------------
template <int MODE>
__global__ void __launch_bounds__(256)
gemm_k64(const __bf16* __restrict__ A, const __bf16* __restrict__ Bt,
         const float* __restrict__ bias, int K, int N,
         float* __restrict__ outf, __bf16* __restrict__ outb,
         const void* __restrict__ res) {
  constexpr int TN = 64, NT = 2;
  __shared__ __align__(16) __bf16 sA[2][128 * 32];
  __shared__ __align__(16) __bf16 sB[2][TN * 32];
  int tid = threadIdx.x, lane = tid & 63, wid = tid >> 6;
  int wm = wid >> 1, wn = wid & 1;
  int quad = lane >> 4, l16 = lane & 15;
  long tileM = (long)blockIdx.x * 128;
  long tileN = (long)blockIdx.y * TN;

  f32x4 acc[4][NT];
  #pragma unroll
  for (int i = 0; i < 4; i++)
    #pragma unroll
    for (int j = 0; j < NT; j++) acc[i][j] = (f32x4){0.f, 0.f, 0.f, 0.f};

  int rr = wid * 16 + (lane >> 2);
  int sc = ((lane & 3) - (lane >> 3)) & 3;       // swizzled staging chunk
  const __bf16* gA = A  + (tileM + rr) * (long)K + (sc << 3);
  const __bf16* gB = Bt + (tileN + rr) * (long)K + (sc << 3);
  const long rowskip = 64 * (long)K;
  int slot = (((l16 >> 1) + quad) & 3) << 3;     // reader slot (elements)

  for (int k0 = 0; k0 < K; k0 += 64) {
    #pragma unroll
    for (int h = 0; h < 2; h++) {
      const int ko = k0 + h * 32;
      gload_lds16(gA + ko,           &sA[h][wid << 9]);
      gload_lds16(gA + ko + rowskip, &sA[h][(wid + 4) << 9]);
      gload_lds16(gB + ko,           &sB[h][wid << 9]);
    }
    __syncthreads();
    #pragma unroll
    for (int h = 0; h < 2; h++) {
      bf16x8 af[4], bfr[NT];
      #pragma unroll
      for (int mt = 0; mt < 4; mt++)
        af[mt] = *(const bf16x8*)(&sA[h][((wm * 64 + mt * 16 + l16) << 5) + slot]);
      #pragma unroll
      for (int nt = 0; nt < NT; nt++)
        bfr[nt] = *(const bf16x8*)(&sB[h][((wn * 32 + nt * 16 + l16) << 5) + slot]);
      #pragma unroll
      for (int mt = 0; mt < 4; mt++)
        #pragma unroll
        for (int nt = 0; nt < NT; nt++)
          acc[mt][nt] = __builtin_amdgcn_mfma_f32_16x16x32_bf16(af[mt], bfr[nt], acc[mt][nt], 0, 0, 0);
    }
    __syncthreads();
  }

  float bcol[NT];
  #pragma unroll
  for (int nt = 0; nt < NT; nt++) bcol[nt] = bias[tileN + wn * 32 + nt * 16 + l16];

  #pragma unroll
  for (int mt = 0; mt < 4; mt++) {
    #pragma unroll
    for (int r = 0; r < 4; r++) {
      long row = tileM + wm * 64 + mt * 16 + quad * 4 + r;
      if (MODE == 0) {
        __bf16* orow = outb + row * (long)N;
        #pragma unroll
        for (int nt = 0; nt < NT; nt++)
          orow[tileN + wn * 32 + nt * 16 + l16] = (__bf16)(acc[mt][nt][r] + bcol[nt]);
      } else if (MODE == 2) {
        __bf16* orow = outb + row * (long)N;
        #pragma unroll
        for (int nt = 0; nt < NT; nt++) {
          float v = acc[mt][nt][r] + bcol[nt];
          orow[tileN + wn * 32 + nt * 16 + l16] = (__bf16)gelu_fast(v);
        }
      } else if (MODE == 4) {  // f32 out, bf16 residual
        float* orow = outf + row * (long)N;
        const __bf16* rrow = (const __bf16*)res + row * (long)N;
        #pragma unroll
        for (int nt = 0; nt < NT; nt++) {
          long col = tileN + wn * 32 + nt * 16 + l16;
          orow[col] = acc[mt][nt][r] + bcol[nt] + (float)rrow[col];
        }
      } else {                 // MODE 5: bf16 out, f32 residual
        __bf16* orow = outb + row * (long)N;
        const float* rrow = (const float*)res + row * (long)N;
        #pragma unroll
        for (int nt = 0; nt < NT; nt++) {
          long col = tileN + wn * 32 + nt * 16 + l16;
          orow[col] = (__bf16)(acc[mt][nt][r] + bcol[nt] + rrow[col]);
        }
      }
    }
  }
}

// ---------------------------------------------------------------------------
extern "C" void kernel_launch(void* const* d_in, const int* in_sizes, int n_in,
                              void* d_out, int out_size, void* d_ws, size_t ws_size,
                              hipStream_t stream) {
  const float* x       = (const float*)d_in[0];
  const float* ln1_g   = (const float*)d_in[1];
  const float* ln1_b   = (const float*)d_in[2];
  const float* qkv_w   = (const float*)d_in[3];
  const float* qkv_b   = (const float*)d_in[4];
  const float* proj_w  = (const float*)d_in[5];
  const float* proj_b  = (const float*)d_in[6];
  const float* attn_b  = (const float*)d_in[7];
  const float* conv_w  = (const float*)d_in[8];
  const float* bn_g    = (const float*)d_in[9];
  const float* bn_b    = (const float*)d_in[10];
  const float* bn_mean = (const float*)d_in[11];
  const float* bn_var  = (const float*)d_in[12];
  const float* ln2_g   = (const float*)d_in[13];
  const float* ln2_b   = (const float*)d_in[14];
  const float* fc1_w   = (const float*)d_in[15];
  const float* fc1_b   = (const float*)d_in[16];
  const float* fc2_w   = (const float*)d_in[17];
  const float* fc2_b   = (const float*)d_in[18];

  // workspace layout (token-compact; aliasing):
  char* p = (char*)d_ws;
  __bf16* WQKV = (__bf16*)p;  p += 884736;     // 1152x384
  __bf16* WPROJ = (__bf16*)p; p += 294912;     // 384x384
  __bf16* WFC1 = (__bf16*)p;  p += 1179648;    // 1536x384
  __bf16* WFC2 = (__bf16*)p;  p += 1179648;    // 384x1536
  float*  WCONV = (float*)p;  p += 13824;      // 9x384
  char* region = p;           p += 63307776;
  float* BMbuf = (float*)p;   p += 196608;     // 12x64x64 bias table
  __bf16* X1 = (__bf16*)p;    p += 12582912;   // bf16 now
  __bf16* X2 = (__bf16*)p;    p += 12582912;
  __bf16* XN   = (__bf16*)region;                 // 16512x384 (dead after qkv)
  __bf16* QKVB = (__bf16*)(region + 12681216);    // 16512x1152
  __bf16* OBUF = (__bf16*)(region + 50724864);    // 16384x384 (token order)
  __bf16* XLN2 = (__bf16*)region;                 // 16384x384 (aliases XN, dead)
  __bf16* H1   = (__bf16*)(region + 12681216);    // 16384x1536 (aliases QKVB+OBUF, dead)
  float*  BM   = BMbuf;
  float* OUT = (float*)d_out;

  prep_all<<<B_TOTAL, 256, 0, stream>>>(x, ln1_g, ln1_b, XN,
                                        qkv_w, WQKV, proj_w, WPROJ,
                                        fc1_w, WFC1, fc2_w, WFC2,
                                        conv_w, WCONV, attn_b, BM);

  // qkv: M=16512 (tokens + pad row), K=384, N=1152   (BK=64, TN=64)
  gemm_k64<0><<<dim3(MQKV / 128, QKVD / 64), 256, 0, stream>>>(
      XN, WQKV, qkv_b, DIM_, QKVD, nullptr, QKVB, nullptr);

  attn_mfma<<<NWIN * 12, 64, 0, stream>>>(QKVB, BM, OBUF);

  // proj: M=16384, K=384, N=384; X1(bf16) = x + OBUF@Wp + b   (BK=64)
  gemm_k64<5><<<dim3(TOKENS / 128, DIM_ / 64), 256, 0, stream>>>(
      OBUF, WPROJ, proj_b, DIM_, DIM_, nullptr, X1, x);

  conv_bn_ln2<<<TOKENS / 4, 384, 0, stream>>>(X1, WCONV, bn_g, bn_b, bn_mean, bn_var,
                                              ln2_g, ln2_b, X2, XLN2);

  // fc1: M=16384, K=384, N=1536, gelu   (BK=64, TN=64)
  gemm_k64<2><<<dim3(TOKENS / 128, HIDD / 64), 256, 0, stream>>>(
      XLN2, WFC1, fc1_b, DIM_, HIDD, nullptr, H1, nullptr);

  // fc2: M=16384, K=1536, N=384, + bf16 residual -> OUT   (BK=64)
  gemm_k64<4><<<dim3(TOKENS / 128, DIM_ / 64), 256, 0, stream>>>(
      H1, WFC2, fc2_b, HIDD, DIM_, OUT, nullptr, X2);
}

// Round 15
// 272.706 us; speedup vs baseline: 1.0412x; 1.0412x over previous
//
#include <hip/hip_runtime.h>
#include <cstdint>

// ---------------------------------------------------------------------------
// TinyViT block on gfx950. Round 15: revert qkv to TN=128/BK=32 gemm_bf16
// (round-14's TN=64 qkv re-read A 18x -> 116MB HBM fetch, +14us). Keep
// round-14's X1/X2 bf16, MODE-5 proj, gemm_k64 for proj/fc1/fc2, swizzled
// LDS (verified conflict-free: SQ_LDS_BANK_CONFLICT=0), fused prep,
// token-gather MFMA attention.
// ---------------------------------------------------------------------------

typedef __bf16 bf16x8 __attribute__((ext_vector_type(8)));
typedef __bf16 bf16x4 __attribute__((ext_vector_type(4)));
typedef float  f32x4  __attribute__((ext_vector_type(4)));

#define DIM_    384
#define QKVD    1152
#define HIDD    1536
#define NTOK    49
#define NWIN    400
#define TOKENS  16384     /* 4*4096 real tokens */
#define PADROW  16384     /* shared pad-token row index */
#define MQKV    16512     /* 129*128 */
#define SCALE_  0.17677669529663689f
#define EPS_    1e-5f

// prep job block ranges (256 threads each)
#define B_LN1   8192      /* 16384 tokens, 2 per block */
#define B_PADR  1
#define B_TQKV  108       /* 64x64 tiles: 6 x 18 */
#define B_TPROJ 36        /* 6 x 6   */
#define B_TFC1  144       /* 6 x 24  */
#define B_TFC2  144       /* 24 x 6  */
#define B_CONV  14
#define B_BIAS  192
#define B_TOTAL (B_LN1 + B_PADR + B_TQKV + B_TPROJ + B_TFC1 + B_TFC2 + B_CONV + B_BIAS)

__device__ __forceinline__ void gload_lds16(const void* g, void* l) {
  __builtin_amdgcn_global_load_lds(
      (__attribute__((address_space(1))) void*)g,
      (__attribute__((address_space(3))) void*)l, 16, 0, 0);
}

// tanh-form GELU via sigmoid + fast rcp
__device__ __forceinline__ float gelu_fast(float v) {
  float t2 = v * (1.5957691216057308f + 0.07135481627f * v * v);
  return v * __builtin_amdgcn_rcpf(1.f + __expf(-t2));
}

// 64x64 tile transpose: src (KxN fp32) -> dst (NxK bf16), coalesced both sides.
__device__ __forceinline__ void tile_transpose(
    const float* __restrict__ src, __bf16* __restrict__ dst,
    int K, int N, int tile, int tilesN, __bf16 (*ld)[65]) {
  int kt = tile / tilesN, nt = tile % tilesN;
  int k0 = kt * 64, n0 = nt * 64;
  int tid = threadIdx.x;
  int a = tid & 63, b4 = tid >> 6;
  #pragma unroll
  for (int i = 0; i < 16; i++) {
    int kl = b4 + i * 4;
    ld[kl][a] = (__bf16)src[(long)(k0 + kl) * N + n0 + a];   // coalesced read
  }
  __syncthreads();
  #pragma unroll
  for (int i = 0; i < 16; i++) {
    int nl = b4 + i * 4;
    dst[(long)(n0 + nl) * K + k0 + a] = ld[a][nl];           // coalesced write
  }
}

// ---------------------------------------------------------------------------
// Fused prep: LN1, shared pad row, tiled weight transposes, conv-w, bias.
// ---------------------------------------------------------------------------
__global__ __launch_bounds__(256) void prep_all(
    const float* __restrict__ x, const float* __restrict__ ln1_g,
    const float* __restrict__ ln1_b, __bf16* __restrict__ xn,
    const float* __restrict__ qkv_w,  __bf16* __restrict__ wqkv,
    const float* __restrict__ proj_w, __bf16* __restrict__ wproj,
    const float* __restrict__ fc1_w,  __bf16* __restrict__ wfc1,
    const float* __restrict__ fc2_w,  __bf16* __restrict__ wfc2,
    const float* __restrict__ conv_w, float* __restrict__ wconv,
    const float* __restrict__ attn_b, float* __restrict__ bm) {
  __shared__ __bf16 tlds[64][65];
  __shared__ float red[2][4];
  int b = blockIdx.x;
  int tid = threadIdx.x;

  if (b < B_LN1) {
    int sub = tid >> 7, tl = tid & 127;
    long t = (long)b * 2 + sub;                // 0..16383
    const float* xr = x + t * DIM_;
    float v0 = xr[tl], v1 = xr[tl + 128], v2 = xr[tl + 256];
    float s = v0 + v1 + v2, s2 = v0 * v0 + v1 * v1 + v2 * v2;
    for (int off = 32; off; off >>= 1) { s += __shfl_down(s, off); s2 += __shfl_down(s2, off); }
    if ((tl & 63) == 0) { red[sub][tl >> 6] = s; red[sub][2 + (tl >> 6)] = s2; }
    __syncthreads();
    float S = red[sub][0] + red[sub][1], S2 = red[sub][2] + red[sub][3];
    float m  = S * (1.f / DIM_);
    float rs = rsqrtf(S2 * (1.f / DIM_) - m * m + EPS_);
    __bf16* orow = xn + t * DIM_;
    orow[tl]       = (__bf16)((v0 - m) * rs * ln1_g[tl]       + ln1_b[tl]);
    orow[tl + 128] = (__bf16)((v1 - m) * rs * ln1_g[tl + 128] + ln1_b[tl + 128]);
    orow[tl + 256] = (__bf16)((v2 - m) * rs * ln1_g[tl + 256] + ln1_b[tl + 256]);
    return;
  }
  b -= B_LN1;
  if (b < B_PADR) {              // shared pad-token row: LN(0-pad) = ln1_b
    for (int i = tid; i < DIM_; i += 256)
      xn[(long)PADROW * DIM_ + i] = (__bf16)ln1_b[i];
    return;
  }
  b -= B_PADR;
  if (b < B_TQKV)  { tile_transpose(qkv_w,  wqkv,  DIM_, QKVD, b, 18, tlds); return; }
  b -= B_TQKV;
  if (b < B_TPROJ) { tile_transpose(proj_w, wproj, DIM_, DIM_, b, 6,  tlds); return; }
  b -= B_TPROJ;
  if (b < B_TFC1)  { tile_transpose(fc1_w,  wfc1,  DIM_, HIDD, b, 24, tlds); return; }
  b -= B_TFC1;
  if (b < B_TFC2)  { tile_transpose(fc2_w,  wfc2,  HIDD, DIM_, b, 6,  tlds); return; }
  b -= B_TFC2;
  if (b < B_CONV) {              // conv_w [384][9] -> wconv [9][384]
    int id = b * 256 + tid;
    if (id < 3456) {
      int ch = id / 9, k = id % 9;
      wconv[k * DIM_ + ch] = conv_w[id];
    }
    return;
  }
  b -= B_CONV;
  {                              // bias table bm[12][64][64], mask kk>=49
    int id = b * 256 + tid;
    int h = id >> 12, q = (id >> 6) & 63, kk = id & 63;
    float v;
    if (kk >= NTOK)      v = -1e30f;
    else if (q >= NTOK)  v = 0.f;
    else {
      int idx = abs(q / 7 - kk / 7) * 7 + abs(q % 7 - kk % 7);
      v = attn_b[h * NTOK + idx];
    }
    bm[id] = v;
  }
}

// ---------------------------------------------------------------------------
// Fused depthwise 3x3 conv + BN + LN2. Block = 4 pixels x 96 lanes (384 thr).
// X1 input bf16; X2 (fc2 residual) and XLN2 written bf16.
// ---------------------------------------------------------------------------
__global__ __launch_bounds__(384) void conv_bn_ln2(
    const __bf16* __restrict__ x1, const float* __restrict__ wT,
    const float* __restrict__ bng, const float* __restrict__ bnb,
    const float* __restrict__ mean, const float* __restrict__ var,
    const float* __restrict__ g2, const float* __restrict__ b2,
    __bf16* __restrict__ x2, __bf16* __restrict__ xln2) {
  int tid = threadIdx.x;
  int p = tid / 96, g = tid % 96;
  int pix = blockIdx.x * 4 + p;            // 0..16383
  int bb = pix >> 12, rc = pix & 4095;
  int r = rc >> 6, c = rc & 63;
  int ch = g << 2;

  f32x4 acc = (f32x4){0.f, 0.f, 0.f, 0.f};
  #pragma unroll
  for (int dr = -1; dr <= 1; dr++) {
    int rr = r + dr;
    if (rr < 0 || rr >= 64) continue;
    #pragma unroll
    for (int dc = -1; dc <= 1; dc++) {
      int cc = c + dc;
      if (cc < 0 || cc >= 64) continue;
      bf16x4 xb = *(const bf16x4*)(x1 + ((long)bb * 4096 + rr * 64 + cc) * DIM_ + ch);
      f32x4 wv = *(const f32x4*)(wT + ((dr + 1) * 3 + (dc + 1)) * DIM_ + ch);
      #pragma unroll
      for (int j = 0; j < 4; j++) acc[j] += (float)xb[j] * wv[j];
    }
  }

  f32x4 gv = *(const f32x4*)(bng + ch);
  f32x4 vv = *(const f32x4*)(var + ch);
  f32x4 mv = *(const f32x4*)(mean + ch);
  f32x4 bv = *(const f32x4*)(bnb + ch);
  f32x4 y;
  #pragma unroll
  for (int j = 0; j < 4; j++) {
    float sc = gv[j] * rsqrtf(vv[j] + EPS_);
    y[j] = acc[j] * sc + (bv[j] - mv[j] * sc);
  }
  {
    bf16x4 xv2;
    #pragma unroll
    for (int j = 0; j < 4; j++) xv2[j] = (__bf16)y[j];
    *(bf16x4*)(x2 + (long)pix * DIM_ + ch) = xv2;
  }

  __shared__ float pS[4][96], pS2[4][96], mS[4], rS[4];
  pS[p][g]  = y[0] + y[1] + y[2] + y[3];
  pS2[p][g] = y[0] * y[0] + y[1] * y[1] + y[2] * y[2] + y[3] * y[3];
  __syncthreads();
  if (g < 32) {
    float a  = pS[p][g]  + pS[p][g + 32]  + pS[p][g + 64];
    float a2 = pS2[p][g] + pS2[p][g + 32] + pS2[p][g + 64];
    #pragma unroll
    for (int off = 1; off < 32; off <<= 1) {
      a  += __shfl_xor(a, off);
      a2 += __shfl_xor(a2, off);
    }
    if (g == 0) {
      float m = a * (1.f / DIM_);
      mS[p] = m;
      rS[p] = rsqrtf(a2 * (1.f / DIM_) - m * m + EPS_);
    }
  }
  __syncthreads();
  float m = mS[p], rs = rS[p];
  f32x4 gg = *(const f32x4*)(g2 + ch);
  f32x4 b2v = *(const f32x4*)(b2 + ch);
  bf16x4 ov;
  #pragma unroll
  for (int j = 0; j < 4; j++) ov[j] = (__bf16)((y[j] - m) * rs * gg[j] + b2v[j]);
  *(bf16x4*)(xln2 + (long)pix * DIM_ + ch) = ov;
}

// ---------------------------------------------------------------------------
// MFMA attention, token-gather version (round-9, verified).
// ---------------------------------------------------------------------------
__global__ __launch_bounds__(64) void attn_mfma(const __bf16* __restrict__ qkv,
                                                const float* __restrict__ bm,
                                                __bf16* __restrict__ o) {
  int blk = blockIdx.x;
  int win = blk / 12, h = blk % 12;
  int bb = win / 100, rem = win % 100;
  int wy = rem / 10, wx = rem % 10;
  int lane = threadIdx.x;
  int quad = lane >> 4, l16 = lane & 15;

  __shared__ __align__(16) __bf16 Vt[32][72];   // Vt[d][kk]
  __shared__ __align__(16) __bf16 P[64][72];    // P[q][kk]

  const __bf16* base = qkv + h * 96;

  bf16x8 qf[4], kf[4];
  #pragma unroll
  for (int mt = 0; mt < 4; mt++) {
    int t = mt * 16 + l16;
    int ty = t / 7, tx = t % 7;
    int r = wy * 7 + ty, c = wx * 7 + tx;
    int row = (t < NTOK && r < 64 && c < 64) ? (bb * 4096 + r * 64 + c) : PADROW;
    const __bf16* rp = base + (long)row * QKVD + quad * 8;
    qf[mt] = *(const bf16x8*)(rp);
    kf[mt] = *(const bf16x8*)(rp + 32);
  }
  {
    int t = lane;
    int ty = t / 7, tx = t % 7;
    int r = wy * 7 + ty, c = wx * 7 + tx;
    int row = (t < NTOK && r < 64 && c < 64) ? (bb * 4096 + r * 64 + c) : PADROW;
    const __bf16* vp = base + (long)row * QKVD + 64;
    bf16x8 vv[4];
    #pragma unroll
    for (int i = 0; i < 4; i++) vv[i] = *(const bf16x8*)(vp + i * 8);
    #pragma unroll
    for (int i = 0; i < 4; i++)
      #pragma unroll
      for (int j = 0; j < 8; j++) Vt[i * 8 + j][lane] = vv[i][j];
  }

  f32x4 S[4][4];
  #pragma unroll
  for (int i = 0; i < 4; i++)
    #pragma unroll
    for (int j = 0; j < 4; j++) S[i][j] = (f32x4){0.f, 0.f, 0.f, 0.f};
  #pragma unroll
  for (int mt = 0; mt < 4; mt++)
    #pragma unroll
    for (int nt = 0; nt < 4; nt++)
      S[mt][nt] = __builtin_amdgcn_mfma_f32_16x16x32_bf16(qf[mt], kf[nt], S[mt][nt], 0, 0, 0);

  const float* bmh = bm + h * 4096;
  #pragma unroll
  for (int mt = 0; mt < 4; mt++)
    #pragma unroll
    for (int r = 0; r < 4; r++) {
      int q = mt * 16 + quad * 4 + r;
      #pragma unroll
      for (int nt = 0; nt < 4; nt++)
        S[mt][nt][r] = S[mt][nt][r] * SCALE_ + bmh[q * 64 + nt * 16 + l16];
    }

  #pragma unroll
  for (int mt = 0; mt < 4; mt++)
    #pragma unroll
    for (int r = 0; r < 4; r++) {
      float mx = fmaxf(fmaxf(S[mt][0][r], S[mt][1][r]), fmaxf(S[mt][2][r], S[mt][3][r]));
      #pragma unroll
      for (int off = 1; off < 16; off <<= 1) mx = fmaxf(mx, __shfl_xor(mx, off));
      float sum = 0.f;
      #pragma unroll
      for (int nt = 0; nt < 4; nt++) {
        float e = __expf(S[mt][nt][r] - mx);
        S[mt][nt][r] = e;
        sum += e;
      }
      #pragma unroll
      for (int off = 1; off < 16; off <<= 1) sum += __shfl_xor(sum, off);
      float inv = 1.f / sum;
      #pragma unroll
      for (int nt = 0; nt < 4; nt++) S[mt][nt][r] *= inv;
    }

  #pragma unroll
  for (int mt = 0; mt < 4; mt++)
    #pragma unroll
    for (int r = 0; r < 4; r++) {
      int q = mt * 16 + quad * 4 + r;
      #pragma unroll
      for (int nt = 0; nt < 4; nt++)
        P[q][nt * 16 + l16] = (__bf16)S[mt][nt][r];
    }
  __syncthreads();

  f32x4 O[4][2];
  #pragma unroll
  for (int i = 0; i < 4; i++)
    #pragma unroll
    for (int j = 0; j < 2; j++) O[i][j] = (f32x4){0.f, 0.f, 0.f, 0.f};
  #pragma unroll
  for (int kt = 0; kt < 2; kt++) {
    bf16x8 pf[4], vf[2];
    #pragma unroll
    for (int mt = 0; mt < 4; mt++)
      pf[mt] = *(const bf16x8*)(&P[mt * 16 + l16][kt * 32 + quad * 8]);
    #pragma unroll
    for (int nt = 0; nt < 2; nt++)
      vf[nt] = *(const bf16x8*)(&Vt[nt * 16 + l16][kt * 32 + quad * 8]);
    #pragma unroll
    for (int mt = 0; mt < 4; mt++)
      #pragma unroll
      for (int nt = 0; nt < 2; nt++)
        O[mt][nt] = __builtin_amdgcn_mfma_f32_16x16x32_bf16(pf[mt], vf[nt], O[mt][nt], 0, 0, 0);
  }

  #pragma unroll
  for (int mt = 0; mt < 4; mt++)
    #pragma unroll
    for (int r = 0; r < 4; r++) {
      int q = mt * 16 + quad * 4 + r;
      if (q < NTOK) {
        int ty = q / 7, tx = q % 7;
        int rr = wy * 7 + ty, cc = wx * 7 + tx;
        if (rr < 64 && cc < 64) {
          __bf16* ob = o + ((long)bb * 4096 + rr * 64 + cc) * DIM_ + h * 32;
          #pragma unroll
          for (int nt = 0; nt < 2; nt++)
            ob[nt * 16 + l16] = (__bf16)O[mt][nt][r];
        }
      }
    }
}

// ---------------------------------------------------------------------------
// bf16 MFMA GEMM (BK=32, swizzled LDS). C(MxN) = A(MxK) @ Bt(NxK)^T.
// Used for qkv only (TN=128 keeps A re-reads at 9x -> L3-resident).
// ---------------------------------------------------------------------------
template <int MODE, int TN>
__global__ void __launch_bounds__(256)
gemm_bf16(const __bf16* __restrict__ A, const __bf16* __restrict__ Bt,
          const float* __restrict__ bias, int K, int N,
          float* __restrict__ outf, __bf16* __restrict__ outb,
          const float* __restrict__ res) {
  constexpr int NT = TN / 32;
  __shared__ __align__(16) __bf16 sA[128 * 32];
  __shared__ __align__(16) __bf16 sB[TN * 32];
  int tid = threadIdx.x, lane = tid & 63, wid = tid >> 6;
  int wm = wid >> 1, wn = wid & 1;
  int quad = lane >> 4, l16 = lane & 15;
  long tileM = (long)blockIdx.x * 128;
  long tileN = (long)blockIdx.y * TN;

  f32x4 acc[4][NT];
  #pragma unroll
  for (int i = 0; i < 4; i++)
    #pragma unroll
    for (int j = 0; j < NT; j++) acc[i][j] = (f32x4){0.f, 0.f, 0.f, 0.f};

  int rr = wid * 16 + (lane >> 2);
  int sc = ((lane & 3) - (lane >> 3)) & 3;       // swizzled staging chunk
  const __bf16* gA = A  + (tileM + rr) * (long)K + (sc << 3);
  const __bf16* gB = Bt + (tileN + rr) * (long)K + (sc << 3);
  const long rowskip = 64 * (long)K;
  int slot = (((l16 >> 1) + quad) & 3) << 3;     // reader slot (elements)

  for (int k0 = 0; k0 < K; k0 += 32) {
    gload_lds16(gA + k0,           sA + (wid << 9));
    gload_lds16(gA + k0 + rowskip, sA + ((wid + 4) << 9));
    gload_lds16(gB + k0,           sB + (wid << 9));
    if (TN == 128)
      gload_lds16(gB + k0 + rowskip, sB + ((wid + 4) << 9));
    __syncthreads();
    bf16x8 af[4], bfr[NT];
    #pragma unroll
    for (int mt = 0; mt < 4; mt++)
      af[mt] = *(const bf16x8*)(sA + ((wm * 64 + mt * 16 + l16) << 5) + slot);
    #pragma unroll
    for (int nt = 0; nt < NT; nt++)
      bfr[nt] = *(const bf16x8*)(sB + ((wn * (TN / 2) + nt * 16 + l16) << 5) + slot);
    #pragma unroll
    for (int mt = 0; mt < 4; mt++)
      #pragma unroll
      for (int nt = 0; nt < NT; nt++)
        acc[mt][nt] = __builtin_amdgcn_mfma_f32_16x16x32_bf16(af[mt], bfr[nt], acc[mt][nt], 0, 0, 0);
    __syncthreads();
  }

  float bcol[NT];
  #pragma unroll
  for (int nt = 0; nt < NT; nt++) bcol[nt] = bias[tileN + wn * (TN / 2) + nt * 16 + l16];

  #pragma unroll
  for (int mt = 0; mt < 4; mt++) {
    #pragma unroll
    for (int r = 0; r < 4; r++) {
      long row = tileM + wm * 64 + mt * 16 + quad * 4 + r;
      if (MODE == 0) {
        __bf16* orow = outb + row * (long)N;
        #pragma unroll
        for (int nt = 0; nt < NT; nt++)
          orow[tileN + wn * (TN / 2) + nt * 16 + l16] = (__bf16)(acc[mt][nt][r] + bcol[nt]);
      } else if (MODE == 2) {
        __bf16* orow = outb + row * (long)N;
        #pragma unroll
        for (int nt = 0; nt < NT; nt++) {
          float v = acc[mt][nt][r] + bcol[nt];
          orow[tileN + wn * (TN / 2) + nt * 16 + l16] = (__bf16)gelu_fast(v);
        }
      } else {
        float* orow = outf + row * (long)N;
        const float* rrow = res + row * (long)N;
        #pragma unroll
        for (int nt = 0; nt < NT; nt++) {
          long col = tileN + wn * (TN / 2) + nt * 16 + l16;
          orow[col] = acc[mt][nt][r] + bcol[nt] + rrow[col];
        }
      }
    }
  }
}

// ---------------------------------------------------------------------------
// BK=64 dual-buffer GEMM, TN=64 (24KB LDS), swizzled LDS layout.
// Used for proj/fc1/fc2 (narrow-N or long-K; A re-reads stay L3-resident).
// MODE 2: bf16 out = gelu_fast(acc + bias)      (fc1)
// MODE 4: f32  out = acc + bias + bf16 res      (fc2 -> OUT)
// MODE 5: bf16 out = acc + bias + f32 res       (proj -> X1)
// K must be a multiple of 64.
// ---------------------------------------------------------------------------
template <int MODE>
__global__ void __launch_bounds__(256)
gemm_k64(const __bf16* __restrict__ A, const __bf16* __restrict__ Bt,
         const float* __restrict__ bias, int K, int N,
         float* __restrict__ outf, __bf16* __restrict__ outb,
         const void* __restrict__ res) {
  constexpr int TN = 64, NT = 2;
  __shared__ __align__(16) __bf16 sA[2][128 * 32];
  __shared__ __align__(16) __bf16 sB[2][TN * 32];
  int tid = threadIdx.x, lane = tid & 63, wid = tid >> 6;
  int wm = wid >> 1, wn = wid & 1;
  int quad = lane >> 4, l16 = lane & 15;
  long tileM = (long)blockIdx.x * 128;
  long tileN = (long)blockIdx.y * TN;

  f32x4 acc[4][NT];
  #pragma unroll
  for (int i = 0; i < 4; i++)
    #pragma unroll
    for (int j = 0; j < NT; j++) acc[i][j] = (f32x4){0.f, 0.f, 0.f, 0.f};

  int rr = wid * 16 + (lane >> 2);
  int sc = ((lane & 3) - (lane >> 3)) & 3;       // swizzled staging chunk
  const __bf16* gA = A  + (tileM + rr) * (long)K + (sc << 3);
  const __bf16* gB = Bt + (tileN + rr) * (long)K + (sc << 3);
  const long rowskip = 64 * (long)K;
  int slot = (((l16 >> 1) + quad) & 3) << 3;     // reader slot (elements)

  for (int k0 = 0; k0 < K; k0 += 64) {
    #pragma unroll
    for (int h = 0; h < 2; h++) {
      const int ko = k0 + h * 32;
      gload_lds16(gA + ko,           &sA[h][wid << 9]);
      gload_lds16(gA + ko + rowskip, &sA[h][(wid + 4) << 9]);
      gload_lds16(gB + ko,           &sB[h][wid << 9]);
    }
    __syncthreads();
    #pragma unroll
    for (int h = 0; h < 2; h++) {
      bf16x8 af[4], bfr[NT];
      #pragma unroll
      for (int mt = 0; mt < 4; mt++)
        af[mt] = *(const bf16x8*)(&sA[h][((wm * 64 + mt * 16 + l16) << 5) + slot]);
      #pragma unroll
      for (int nt = 0; nt < NT; nt++)
        bfr[nt] = *(const bf16x8*)(&sB[h][((wn * 32 + nt * 16 + l16) << 5) + slot]);
      #pragma unroll
      for (int mt = 0; mt < 4; mt++)
        #pragma unroll
        for (int nt = 0; nt < NT; nt++)
          acc[mt][nt] = __builtin_amdgcn_mfma_f32_16x16x32_bf16(af[mt], bfr[nt], acc[mt][nt], 0, 0, 0);
    }
    __syncthreads();
  }

  float bcol[NT];
  #pragma unroll
  for (int nt = 0; nt < NT; nt++) bcol[nt] = bias[tileN + wn * 32 + nt * 16 + l16];

  #pragma unroll
  for (int mt = 0; mt < 4; mt++) {
    #pragma unroll
    for (int r = 0; r < 4; r++) {
      long row = tileM + wm * 64 + mt * 16 + quad * 4 + r;
      if (MODE == 2) {
        __bf16* orow = outb + row * (long)N;
        #pragma unroll
        for (int nt = 0; nt < NT; nt++) {
          float v = acc[mt][nt][r] + bcol[nt];
          orow[tileN + wn * 32 + nt * 16 + l16] = (__bf16)gelu_fast(v);
        }
      } else if (MODE == 4) {  // f32 out, bf16 residual
        float* orow = outf + row * (long)N;
        const __bf16* rrow = (const __bf16*)res + row * (long)N;
        #pragma unroll
        for (int nt = 0; nt < NT; nt++) {
          long col = tileN + wn * 32 + nt * 16 + l16;
          orow[col] = acc[mt][nt][r] + bcol[nt] + (float)rrow[col];
        }
      } else {                 // MODE 5: bf16 out, f32 residual
        __bf16* orow = outb + row * (long)N;
        const float* rrow = (const float*)res + row * (long)N;
        #pragma unroll
        for (int nt = 0; nt < NT; nt++) {
          long col = tileN + wn * 32 + nt * 16 + l16;
          orow[col] = (__bf16)(acc[mt][nt][r] + bcol[nt] + rrow[col]);
        }
      }
    }
  }
}

// ---------------------------------------------------------------------------
extern "C" void kernel_launch(void* const* d_in, const int* in_sizes, int n_in,
                              void* d_out, int out_size, void* d_ws, size_t ws_size,
                              hipStream_t stream) {
  const float* x       = (const float*)d_in[0];
  const float* ln1_g   = (const float*)d_in[1];
  const float* ln1_b   = (const float*)d_in[2];
  const float* qkv_w   = (const float*)d_in[3];
  const float* qkv_b   = (const float*)d_in[4];
  const float* proj_w  = (const float*)d_in[5];
  const float* proj_b  = (const float*)d_in[6];
  const float* attn_b  = (const float*)d_in[7];
  const float* conv_w  = (const float*)d_in[8];
  const float* bn_g    = (const float*)d_in[9];
  const float* bn_b    = (const float*)d_in[10];
  const float* bn_mean = (const float*)d_in[11];
  const float* bn_var  = (const float*)d_in[12];
  const float* ln2_g   = (const float*)d_in[13];
  const float* ln2_b   = (const float*)d_in[14];
  const float* fc1_w   = (const float*)d_in[15];
  const float* fc1_b   = (const float*)d_in[16];
  const float* fc2_w   = (const float*)d_in[17];
  const float* fc2_b   = (const float*)d_in[18];

  // workspace layout (token-compact; aliasing):
  char* p = (char*)d_ws;
  __bf16* WQKV = (__bf16*)p;  p += 884736;     // 1152x384
  __bf16* WPROJ = (__bf16*)p; p += 294912;     // 384x384
  __bf16* WFC1 = (__bf16*)p;  p += 1179648;    // 1536x384
  __bf16* WFC2 = (__bf16*)p;  p += 1179648;    // 384x1536
  float*  WCONV = (float*)p;  p += 13824;      // 9x384
  char* region = p;           p += 63307776;
  float* BMbuf = (float*)p;   p += 196608;     // 12x64x64 bias table
  __bf16* X1 = (__bf16*)p;    p += 12582912;   // bf16
  __bf16* X2 = (__bf16*)p;    p += 12582912;   // bf16
  __bf16* XN   = (__bf16*)region;                 // 16512x384 (dead after qkv)
  __bf16* QKVB = (__bf16*)(region + 12681216);    // 16512x1152
  __bf16* OBUF = (__bf16*)(region + 50724864);    // 16384x384 (token order)
  __bf16* XLN2 = (__bf16*)region;                 // 16384x384 (aliases XN, dead)
  __bf16* H1   = (__bf16*)(region + 12681216);    // 16384x1536 (aliases QKVB+OBUF, dead)
  float*  BM   = BMbuf;
  float* OUT = (float*)d_out;

  prep_all<<<B_TOTAL, 256, 0, stream>>>(x, ln1_g, ln1_b, XN,
                                        qkv_w, WQKV, proj_w, WPROJ,
                                        fc1_w, WFC1, fc2_w, WFC2,
                                        conv_w, WCONV, attn_b, BM);

  // qkv: M=16512 (tokens + pad row), K=384, N=1152   (TN=128, BK=32)
  gemm_bf16<0, 128><<<dim3(MQKV / 128, QKVD / 128), 256, 0, stream>>>(
      XN, WQKV, qkv_b, DIM_, QKVD, nullptr, QKVB, nullptr);

  attn_mfma<<<NWIN * 12, 64, 0, stream>>>(QKVB, BM, OBUF);

  // proj: M=16384, K=384, N=384; X1(bf16) = x + OBUF@Wp + b   (BK=64)
  gemm_k64<5><<<dim3(TOKENS / 128, DIM_ / 64), 256, 0, stream>>>(
      OBUF, WPROJ, proj_b, DIM_, DIM_, nullptr, X1, x);

  conv_bn_ln2<<<TOKENS / 4, 384, 0, stream>>>(X1, WCONV, bn_g, bn_b, bn_mean, bn_var,
                                              ln2_g, ln2_b, X2, XLN2);

  // fc1: M=16384, K=384, N=1536, gelu   (BK=64, TN=64)
  gemm_k64<2><<<dim3(TOKENS / 128, HIDD / 64), 256, 0, stream>>>(
      XLN2, WFC1, fc1_b, DIM_, HIDD, nullptr, H1, nullptr);

  // fc2: M=16384, K=1536, N=384, + bf16 residual -> OUT   (BK=64)
  gemm_k64<4><<<dim3(TOKENS / 128, DIM_ / 64), 256, 0, stream>>>(
      H1, WFC2, fc2_b, HIDD, DIM_, OUT, nullptr, X2);
}